// Round 2
// baseline (330.280 us; speedup 1.0000x reference)
//
#include <hip/hip_runtime.h>

// HistogramLoss on MI355X — fused pairwise-cosine + soft-histogram + loss.
// Round 2: fp32 register-tiled GEMM (no fp32 MFMA on CDNA4) with fused
// binning epilogue into privatized LDS histograms.
// Fix vs round 1: split swizzled reads (pa0/pa1) — swz() moves rows at
// float4 granularity, so the 2nd half of an 8-row group is at swz(base+4),
// NOT swz(base)+4. Also: parallel finalize (scan+reduce) instead of serial.

#define N_PTS   4096
#define DIM     512
#define TSIZE   151
#define HALF_T  75
#define BM      128
#define BK      32
#define NTILES  (N_PTS / BM)                    // 32
#define NBLOCKS (NTILES * (NTILES + 1) / 2)     // 528
#define LDS_STRIDE 132                          // 528B rows: 16B-aligned, bank-rotating
#define NCOPY   8                               // privatized histogram copies
#define HSTRIDE 309                             // 2*151=302 padded to odd -> copies shift banks
#define P_TOTAL 8386560u                        // 4096*4095/2
#define STEPF   (2.0f / 150.0f)

// XOR-swizzle: fold col bits 5,6 into bits 2,3 (float4-granular row displacement)
// so the 16 distinct B-read addresses spread 2-way instead of 4-way per bank group.
__device__ __forceinline__ int swz(int c) { return c ^ ((c & 0x60) >> 3); }

__global__ __launch_bounds__(256) void hist_kernel(
    const float* __restrict__ F, const int* __restrict__ cls,
    float* __restrict__ g_hist, unsigned int* __restrict__ g_pos)
{
  __shared__ __align__(16) float As[BK * LDS_STRIDE];
  __shared__ __align__(16) float Bs[BK * LDS_STRIDE];
  __shared__ float hist[NCOPY * HSTRIDE];
  __shared__ int clsA[BM];
  __shared__ int clsB[BM];
  __shared__ unsigned int posCount;

  const int t = threadIdx.x;

  // decode upper-triangular tile index (uniform scalar loop, <=32 iters)
  int rem = (int)blockIdx.x, cnt = NTILES, bi = 0;
  while (rem >= cnt) { rem -= cnt; --cnt; ++bi; }
  const int bj = bi + rem;
  const int rowA = bi * BM, rowB = bj * BM;

  for (int i = t; i < NCOPY * HSTRIDE; i += 256) hist[i] = 0.0f;
  if (t < BM) clsA[t] = cls[rowA + t];
  else        clsB[t - BM] = cls[rowB + (t - BM)];
  if (t == 0) posCount = 0u;

  const int tx = t & 15, ty = t >> 4;
  const int pa0 = swz(ty * 8), pa1 = swz(ty * 8 + 4);
  const int pb0 = swz(tx * 8), pb1 = swz(tx * 8 + 4);

  float acc[8][8];
  #pragma unroll
  for (int i = 0; i < 8; ++i)
    #pragma unroll
    for (int j = 0; j < 8; ++j) acc[i][j] = 0.0f;

  for (int kk = 0; kk < DIM; kk += BK) {
    __syncthreads();
    // stage A/B k-chunk, transposed to [k][row] (swizzled row position)
    #pragma unroll
    for (int m = 0; m < 4; ++m) {
      int q  = t + m * 256;        // 0..1023  (128 rows x 8 float4)
      int r  = q >> 3;             // row 0..127
      int kq = (q & 7) * 4;        // k offset 0..28
      const float4 va = *(const float4*)(F + (size_t)(rowA + r) * DIM + kk + kq);
      const float4 vb = *(const float4*)(F + (size_t)(rowB + r) * DIM + kk + kq);
      int pc = swz(r);
      As[(kq + 0) * LDS_STRIDE + pc] = va.x;
      As[(kq + 1) * LDS_STRIDE + pc] = va.y;
      As[(kq + 2) * LDS_STRIDE + pc] = va.z;
      As[(kq + 3) * LDS_STRIDE + pc] = va.w;
      Bs[(kq + 0) * LDS_STRIDE + pc] = vb.x;
      Bs[(kq + 1) * LDS_STRIDE + pc] = vb.y;
      Bs[(kq + 2) * LDS_STRIDE + pc] = vb.z;
      Bs[(kq + 3) * LDS_STRIDE + pc] = vb.w;
    }
    __syncthreads();
    // 8x8 register-tile FMA over the chunk
    #pragma unroll
    for (int k = 0; k < BK; ++k) {
      const float* ar = As + k * LDS_STRIDE;
      const float* br = Bs + k * LDS_STRIDE;
      const float4 a0 = *(const float4*)(ar + pa0);
      const float4 a1 = *(const float4*)(ar + pa1);
      const float4 b0 = *(const float4*)(br + pb0);
      const float4 b1 = *(const float4*)(br + pb1);
      const float av[8] = {a0.x, a0.y, a0.z, a0.w, a1.x, a1.y, a1.z, a1.w};
      const float bv[8] = {b0.x, b0.y, b0.z, b0.w, b1.x, b1.y, b1.z, b1.w};
      #pragma unroll
      for (int i = 0; i < 8; ++i)
        #pragma unroll
        for (int j = 0; j < 8; ++j)
          acc[i][j] = fmaf(av[i], bv[j], acc[i][j]);
    }
  }

  // ---- fused binning epilogue ----
  // copy = 2 per wave, split by lane half: same hot bin spreads over 8 copies
  float* h = hist + (((t >> 6) << 1) | ((t >> 5) & 1)) * HSTRIDE;
  int ci[8], cj[8];
  #pragma unroll
  for (int i = 0; i < 8; ++i) ci[i] = clsA[ty * 8 + i];
  #pragma unroll
  for (int j = 0; j < 8; ++j) cj[j] = clsB[tx * 8 + j];
  const int gi0 = rowA + ty * 8, gj0 = rowB + tx * 8;

  unsigned int myPos = 0;
  #pragma unroll
  for (int i = 0; i < 8; ++i) {
    #pragma unroll
    for (int j = 0; j < 8; ++j) {
      int gi = gi0 + i, gj = gj0 + j;
      if (gi >= gj) continue;            // only bites on diagonal tiles
      float s  = acc[i][j];
      float jf = floorf(s / STEPF);      // match reference expression order
      int   jb = (int)jf + HALF_T;
      float f  = jf * STEPF;
      float wa = (s - f) / STEPF;
      float wb = (f + STEPF - s) / STEPF;
      bool  pos = (ci[i] == cj[j]);
      myPos += pos ? 1u : 0u;
      int off = pos ? 0 : TSIZE;
      if (jb >= 0 && jb < TSIZE)         atomicAdd(h + off + jb, wa);
      if (jb + 1 >= 0 && jb + 1 < TSIZE) atomicAdd(h + off + jb + 1, wb);
    }
  }
  atomicAdd(&posCount, myPos);
  __syncthreads();

  // reduce 8 copies -> global accumulation
  for (int i = t; i < 2 * TSIZE; i += 256) {
    float v = 0.0f;
    #pragma unroll
    for (int c = 0; c < NCOPY; ++c) v += hist[c * HSTRIDE + i];
    unsafeAtomicAdd(g_hist + i, v);
  }
  if (t == 0) atomicAdd(g_pos, posCount);
}

__global__ void zero_ws(float* g_hist, unsigned int* g_pos) {
  int t = threadIdx.x;
  if (t < 2 * TSIZE) g_hist[t] = 0.0f;
  if (t == 0) *g_pos = 0u;
}

__global__ __launch_bounds__(256) void finalize(
    const float* __restrict__ g_hist,
    const unsigned int* __restrict__ g_pos,
    float* __restrict__ out)
{
  __shared__ float hp[TSIZE];
  __shared__ float hn[TSIZE];
  __shared__ float red[4];
  const int t = threadIdx.x;
  const float Np = (float)(*g_pos);
  const float Nn = (float)(P_TOTAL - *g_pos);
  if (t < TSIZE) {
    hp[t] = g_hist[t] / Np;
    hn[t] = g_hist[TSIZE + t] / Nn;
  }
  __syncthreads();
  // Hillis-Steele inclusive scan over hp
  for (int off = 1; off < TSIZE; off <<= 1) {
    float v = 0.0f;
    if (t < TSIZE && t >= off) v = hp[t - off];
    __syncthreads();
    if (t < TSIZE) hp[t] += v;
    __syncthreads();
  }
  float term = (t < TSIZE) ? hn[t] * hp[t] : 0.0f;
  #pragma unroll
  for (int o = 32; o > 0; o >>= 1) term += __shfl_down(term, o);
  if ((t & 63) == 0) red[t >> 6] = term;
  __syncthreads();
  if (t == 0) *out = red[0] + red[1] + red[2] + red[3];
}

extern "C" void kernel_launch(void* const* d_in, const int* in_sizes, int n_in,
                              void* d_out, int out_size, void* d_ws, size_t ws_size,
                              hipStream_t stream) {
  const float* F   = (const float*)d_in[0];
  const int*   cls = (const int*)d_in[1];
  float*        g_hist = (float*)d_ws;                               // 302 floats
  unsigned int* g_pos  = (unsigned int*)((char*)d_ws + 2 * TSIZE * sizeof(float));
  float* out = (float*)d_out;

  zero_ws<<<1, 512, 0, stream>>>(g_hist, g_pos);
  hist_kernel<<<NBLOCKS, 256, 0, stream>>>(F, cls, g_hist, g_pos);
  finalize<<<1, 256, 0, stream>>>(g_hist, g_pos, out);
}

// Round 4
// 220.341 us; speedup vs baseline: 1.4990x; 1.4990x over previous
//
#include <hip/hip_runtime.h>

// HistogramLoss on MI355X — fused pairwise-cosine + soft-histogram + loss.
// Round 4: split-bf16 MFMA (s ~= hi*hi + lo*hi + hi*lo, fp32 acc) with
// PRE-SPLIT fragment-major operands read straight from L2/L3 (no operand
// LDS, no K-loop barriers). Fallback to LDS-staged version if ws is small.

#define N_PTS   4096
#define DIM     512
#define TSIZE   151
#define HALF_T  75
#define BM      128
#define BK      32
#define NTILES  32
#define NBLOCKS 528                 // 32*33/2, = 8*66 (XCD-bijective)
#define P_TOTAL 8386560u
#define STEPF   (2.0f / 150.0f)
#define STEPINV 75.0f
#define NCOPY   16                  // fast-path hist copies
#define NCOPY_FB 8                  // fallback hist copies
#define HSTRIDE 309                 // 309 mod 32 = 21 (odd): copies bank-distinct

typedef short bfrag __attribute__((ext_vector_type(8)));   // 8 bf16
typedef float ffrag __attribute__((ext_vector_type(4)));   // 4 f32
typedef unsigned short u16;
typedef unsigned int   u32;

__device__ __forceinline__ ffrag mfma16(bfrag a, bfrag b, ffrag c) {
  return __builtin_amdgcn_mfma_f32_16x16x32_bf16(a, b, c, 0, 0, 0);
}

// split float4 -> truncated-bf16 hi + bf16(residual) lo, packed 2/uint
__device__ __forceinline__ void split4(float4 v, uint2* hi, uint2* lo) {
  u32 u0 = __float_as_uint(v.x), u1 = __float_as_uint(v.y);
  u32 u2 = __float_as_uint(v.z), u3 = __float_as_uint(v.w);
  float r0 = v.x - __uint_as_float(u0 & 0xFFFF0000u);   // exact
  float r1 = v.y - __uint_as_float(u1 & 0xFFFF0000u);
  float r2 = v.z - __uint_as_float(u2 & 0xFFFF0000u);
  float r3 = v.w - __uint_as_float(u3 & 0xFFFF0000u);
  hi->x = (u0 >> 16) | (u1 & 0xFFFF0000u);
  hi->y = (u2 >> 16) | (u3 & 0xFFFF0000u);
  lo->x = (__float_as_uint(r0) >> 16) | (__float_as_uint(r1) & 0xFFFF0000u);
  lo->y = (__float_as_uint(r2) >> 16) | (__float_as_uint(r3) & 0xFFFF0000u);
}

// triangular soft-binning of a wave's 4x4 fragment block into LDS hist copy h
__device__ __forceinline__ void bin_epilogue(
    const ffrag (&acc)[4][4], float* h, const int* clsA, const int* clsB,
    int wy, int wx, int l4, int l16, bool diag, u32* myPos)
{
  #pragma unroll
  for (int fi = 0; fi < 4; ++fi) {
    #pragma unroll
    for (int fj = 0; fj < 4; ++fj) {
      #pragma unroll
      for (int r = 0; r < 4; ++r) {
        // C/D layout (m89/m91): row = 4*(lane>>4)+reg, col = lane&15
        int li = wy * 64 + fi * 16 + l4 * 4 + r;
        int lj = wx * 64 + fj * 16 + l16;
        if (diag && li >= lj) continue;
        float s  = acc[fi][fj][r];
        float jf = floorf(s * STEPINV);
        int   jb = (int)jf + HALF_T;
        float f  = jf * STEPF;
        float wa = (s - f) * STEPINV;
        float wb = (f + STEPF - s) * STEPINV;
        bool  pos = (clsA[li] == clsB[lj]);
        *myPos += pos ? 1u : 0u;
        int off = pos ? 0 : TSIZE;
        if (jb >= 0 && jb < TSIZE)         unsafeAtomicAdd(h + off + jb, wa);
        if (jb + 1 >= 0 && jb + 1 < TSIZE) unsafeAtomicAdd(h + off + jb + 1, wb);
      }
    }
  }
}

// decode upper-triangular tile with XCD-aware swizzle (528 = 8*66, bijective)
__device__ __forceinline__ void tile_decode(int orig, int* bi_, int* bj_) {
  int sbid = (orig & 7) * 66 + (orig >> 3);
  int rem = sbid, cnt = NTILES, bi = 0;
  while (rem >= cnt) { rem -= cnt; --cnt; ++bi; }
  *bi_ = bi; *bj_ = bi + rem;
}

// ---- pass 1: split F into fragment-major bf16 hi/lo:  [k/8][row][8] ----
__global__ __launch_bounds__(256) void presplit(
    const float* __restrict__ F, u16* __restrict__ FhiP, u16* __restrict__ FloP)
{
  int u = blockIdx.x * 256 + threadIdx.x;   // u = kb*4096 + row
  int kb = u >> 12, row = u & 4095;
  const float* src = F + (size_t)row * DIM + kb * 8;
  float4 v0 = *(const float4*)(src);
  float4 v1 = *(const float4*)(src + 4);
  uint2 h0, l0, h1, l1;
  split4(v0, &h0, &l0);
  split4(v1, &h1, &l1);
  uint4 hv; hv.x = h0.x; hv.y = h0.y; hv.z = h1.x; hv.w = h1.y;
  uint4 lv; lv.x = l0.x; lv.y = l0.y; lv.z = l1.x; lv.w = l1.y;
  *(uint4*)(FhiP + (size_t)u * 8) = hv;     // coalesced 16B/lane
  *(uint4*)(FloP + (size_t)u * 8) = lv;
}

// ---- pass 2 (fast): fragments direct global->reg, no operand LDS ----
__global__ __launch_bounds__(256, 3) void hist_mfma(
    const u16* __restrict__ FhiP, const u16* __restrict__ FloP,
    const int* __restrict__ cls,
    float* __restrict__ g_hist, u32* __restrict__ g_pos)
{
  __shared__ float hist[NCOPY * HSTRIDE];
  __shared__ int clsA[BM], clsB[BM];
  __shared__ u32 posCount;

  const int t = threadIdx.x;
  int bi, bj;
  tile_decode((int)blockIdx.x, &bi, &bj);
  const int rowA = bi * BM, rowB = bj * BM;

  for (int i = t; i < NCOPY * HSTRIDE; i += 256) hist[i] = 0.0f;
  if (t < BM) clsA[t] = cls[rowA + t];
  else        clsB[t - BM] = cls[rowB + (t - BM)];
  if (t == 0) posCount = 0u;

  const int lane = t & 63, w = t >> 6;
  const int wy = w >> 1, wx = w & 1;          // wave -> 64x64 quadrant
  const int l4 = lane >> 4, l16 = lane & 15;

  ffrag acc[4][4] = {};

  const size_t arow = (size_t)(rowA + wy * 64 + l16);
  const size_t brow = (size_t)(rowB + wx * 64 + l16);

  for (int s = 0; s < DIM / 32; ++s) {
    const size_t kbase = (size_t)(s * 4 + l4) * N_PTS;   // kblock row-plane
    const u16* aph = FhiP + (kbase + arow) * 8;
    const u16* apl = FloP + (kbase + arow) * 8;
    const u16* bph = FhiP + (kbase + brow) * 8;
    const u16* bpl = FloP + (kbase + brow) * 8;
    bfrag ah[4], al[4];
    #pragma unroll
    for (int fi = 0; fi < 4; ++fi) {
      ah[fi] = *(const bfrag*)(aph + fi * 128);   // 16 rows * 8 elems
      al[fi] = *(const bfrag*)(apl + fi * 128);
    }
    #pragma unroll
    for (int fj = 0; fj < 4; ++fj) {
      bfrag bh = *(const bfrag*)(bph + fj * 128);
      bfrag bl = *(const bfrag*)(bpl + fj * 128);
      #pragma unroll
      for (int fi = 0; fi < 4; ++fi) {
        acc[fi][fj] = mfma16(ah[fi], bh, acc[fi][fj]);
        acc[fi][fj] = mfma16(al[fi], bh, acc[fi][fj]);
        acc[fi][fj] = mfma16(ah[fi], bl, acc[fi][fj]);
      }
    }
  }

  __syncthreads();                    // hist/cls init visible (only barrier)
  u32 myPos = 0;
  float* h = hist + l16 * HSTRIDE;    // adjacent lanes -> distinct copies/banks
  bin_epilogue(acc, h, clsA, clsB, wy, wx, l4, l16, bi == bj, &myPos);
  atomicAdd(&posCount, myPos);
  __syncthreads();

  for (int i = t; i < 2 * TSIZE; i += 256) {
    float v = 0.0f;
    #pragma unroll
    for (int c = 0; c < NCOPY; ++c) v += hist[c * HSTRIDE + i];
    unsafeAtomicAdd(g_hist + i, v);
  }
  if (t == 0) atomicAdd(g_pos, posCount);
}

// ---- pass 2 (fallback, small ws): LDS-staged with in-loop split ----
__global__ __launch_bounds__(256, 3) void hist_fb(
    const float* __restrict__ F, const int* __restrict__ cls,
    float* __restrict__ g_hist, u32* __restrict__ g_pos)
{
  __shared__ __align__(16) u16 Ahi[BM * BK];
  __shared__ __align__(16) u16 Alo[BM * BK];
  __shared__ __align__(16) u16 Bhi[BM * BK];
  __shared__ __align__(16) u16 Blo[BM * BK];
  __shared__ float hist[NCOPY_FB * HSTRIDE];
  __shared__ int clsA[BM], clsB[BM];
  __shared__ u32 posCount;

  const int t = threadIdx.x;
  int bi, bj;
  tile_decode((int)blockIdx.x, &bi, &bj);
  const int rowA = bi * BM, rowB = bj * BM;

  for (int i = t; i < NCOPY_FB * HSTRIDE; i += 256) hist[i] = 0.0f;
  if (t < BM) clsA[t] = cls[rowA + t];
  else        clsB[t - BM] = cls[rowB + (t - BM)];
  if (t == 0) posCount = 0u;

  const int lane = t & 63, w = t >> 6;
  const int wy = w >> 1, wx = w & 1;
  const int l4 = lane >> 4, l16 = lane & 15;

  ffrag acc[4][4] = {};

  for (int kk = 0; kk < DIM; kk += BK) {
    __syncthreads();
    #pragma unroll
    for (int m = 0; m < 4; ++m) {
      int q  = t + m * 256;
      int r  = q >> 3;
      int kq = (q & 7) * 4;
      float4 va = *(const float4*)(F + (size_t)(rowA + r) * DIM + kk + kq);
      float4 vb = *(const float4*)(F + (size_t)(rowB + r) * DIM + kk + kq);
      uint2 h, l;
      split4(va, &h, &l);
      *(uint2*)&Ahi[r * BK + kq] = h;
      *(uint2*)&Alo[r * BK + kq] = l;
      split4(vb, &h, &l);
      *(uint2*)&Bhi[r * BK + kq] = h;
      *(uint2*)&Blo[r * BK + kq] = l;
    }
    __syncthreads();

    bfrag ah[4], al[4];
    #pragma unroll
    for (int fi = 0; fi < 4; ++fi) {
      int off = (wy * 64 + fi * 16 + l16) * BK + l4 * 8;
      ah[fi] = *(const bfrag*)&Ahi[off];
      al[fi] = *(const bfrag*)&Alo[off];
    }
    #pragma unroll
    for (int fj = 0; fj < 4; ++fj) {
      int off = (wx * 64 + fj * 16 + l16) * BK + l4 * 8;
      bfrag bh = *(const bfrag*)&Bhi[off];
      bfrag bl = *(const bfrag*)&Blo[off];
      #pragma unroll
      for (int fi = 0; fi < 4; ++fi) {
        acc[fi][fj] = mfma16(ah[fi], bh, acc[fi][fj]);
        acc[fi][fj] = mfma16(al[fi], bh, acc[fi][fj]);
        acc[fi][fj] = mfma16(ah[fi], bl, acc[fi][fj]);
      }
    }
  }

  __syncthreads();
  u32 myPos = 0;
  float* h = hist + (lane & 7) * HSTRIDE;
  bin_epilogue(acc, h, clsA, clsB, wy, wx, l4, l16, bi == bj, &myPos);
  atomicAdd(&posCount, myPos);
  __syncthreads();

  for (int i = t; i < 2 * TSIZE; i += 256) {
    float v = 0.0f;
    #pragma unroll
    for (int c = 0; c < NCOPY_FB; ++c) v += hist[c * HSTRIDE + i];
    unsafeAtomicAdd(g_hist + i, v);
  }
  if (t == 0) atomicAdd(g_pos, posCount);
}

__global__ void zero_ws(float* g_hist, u32* g_pos) {
  int t = threadIdx.x;
  if (t < 2 * TSIZE) g_hist[t] = 0.0f;
  if (t == 0) *g_pos = 0u;
}

__global__ __launch_bounds__(256) void finalize(
    const float* __restrict__ g_hist,
    const u32* __restrict__ g_pos,
    float* __restrict__ out)
{
  __shared__ float hp[TSIZE];
  __shared__ float hn[TSIZE];
  __shared__ float red[4];
  const int t = threadIdx.x;
  const float Np = (float)(*g_pos);
  const float Nn = (float)(P_TOTAL - *g_pos);
  if (t < TSIZE) {
    hp[t] = g_hist[t] / Np;
    hn[t] = g_hist[TSIZE + t] / Nn;
  }
  __syncthreads();
  for (int off = 1; off < TSIZE; off <<= 1) {
    float v = 0.0f;
    if (t < TSIZE && t >= off) v = hp[t - off];
    __syncthreads();
    if (t < TSIZE) hp[t] += v;
    __syncthreads();
  }
  float term = (t < TSIZE) ? hn[t] * hp[t] : 0.0f;
  #pragma unroll
  for (int o = 32; o > 0; o >>= 1) term += __shfl_down(term, o);
  if ((t & 63) == 0) red[t >> 6] = term;
  __syncthreads();
  if (t == 0) *out = red[0] + red[1] + red[2] + red[3];
}

extern "C" void kernel_launch(void* const* d_in, const int* in_sizes, int n_in,
                              void* d_out, int out_size, void* d_ws, size_t ws_size,
                              hipStream_t stream) {
  const float* F   = (const float*)d_in[0];
  const int*   cls = (const int*)d_in[1];
  float* g_hist = (float*)d_ws;
  u32*   g_pos  = (u32*)((char*)d_ws + 2 * TSIZE * sizeof(float));
  float* out = (float*)d_out;

  const size_t offH   = 65536;
  const size_t bytesP = (size_t)N_PTS * DIM * sizeof(u16);   // 4 MB each

  zero_ws<<<1, 512, 0, stream>>>(g_hist, g_pos);
  if (ws_size >= offH + 2 * bytesP) {
    u16* FhiP = (u16*)((char*)d_ws + offH);
    u16* FloP = (u16*)((char*)d_ws + offH + bytesP);
    presplit<<<(N_PTS * DIM / 8) / 256, 256, 0, stream>>>(F, FhiP, FloP);
    hist_mfma<<<NBLOCKS, 256, 0, stream>>>(FhiP, FloP, cls, g_hist, g_pos);
  } else {
    hist_fb<<<NBLOCKS, 256, 0, stream>>>(F, cls, g_hist, g_pos);
  }
  finalize<<<1, 256, 0, stream>>>(g_hist, g_pos, out);
}

// Round 6
// 215.348 us; speedup vs baseline: 1.5337x; 1.0232x over previous
//
#include <hip/hip_runtime.h>

// HistogramLoss on MI355X — fused pairwise-cosine + soft-histogram + loss.
// Round 6 (= Round 5 resubmitted; never ran due to GPU timeout):
// register double-buffered K-pipeline (prefetch step s+1's global fragments
// during step s's 48 MFMAs). Split-bf16 MFMA, pre-split fragment-major
// operands in ws, no operand LDS, no K-loop barriers.

#define N_PTS   4096
#define DIM     512
#define TSIZE   151
#define HALF_T  75
#define BM      128
#define NTILES  32
#define NBLOCKS 528                 // 32*33/2 = 8*66 (XCD-bijective)
#define P_TOTAL 8386560u
#define STEPF   (2.0f / 150.0f)
#define STEPINV 75.0f
#define NCOPY   16
#define HSTRIDE 309                 // mod 32 = 21: copies bank-distinct

typedef short bfrag __attribute__((ext_vector_type(8)));   // 8 bf16
typedef float ffrag __attribute__((ext_vector_type(4)));   // 4 f32
typedef unsigned short u16;
typedef unsigned int   u32;

__device__ __forceinline__ ffrag mfma16(bfrag a, bfrag b, ffrag c) {
  return __builtin_amdgcn_mfma_f32_16x16x32_bf16(a, b, c, 0, 0, 0);
}

__device__ __forceinline__ void split4(float4 v, uint2* hi, uint2* lo) {
  u32 u0 = __float_as_uint(v.x), u1 = __float_as_uint(v.y);
  u32 u2 = __float_as_uint(v.z), u3 = __float_as_uint(v.w);
  float r0 = v.x - __uint_as_float(u0 & 0xFFFF0000u);   // exact residual
  float r1 = v.y - __uint_as_float(u1 & 0xFFFF0000u);
  float r2 = v.z - __uint_as_float(u2 & 0xFFFF0000u);
  float r3 = v.w - __uint_as_float(u3 & 0xFFFF0000u);
  hi->x = (u0 >> 16) | (u1 & 0xFFFF0000u);
  hi->y = (u2 >> 16) | (u3 & 0xFFFF0000u);
  lo->x = (__float_as_uint(r0) >> 16) | (__float_as_uint(r1) & 0xFFFF0000u);
  lo->y = (__float_as_uint(r2) >> 16) | (__float_as_uint(r3) & 0xFFFF0000u);
}

__device__ __forceinline__ void bin_epilogue(
    const ffrag (&acc)[4][4], float* h, const int* clsA, const int* clsB,
    int wy, int wx, int l4, int l16, bool diag, u32* myPos)
{
  #pragma unroll
  for (int fi = 0; fi < 4; ++fi) {
    #pragma unroll
    for (int fj = 0; fj < 4; ++fj) {
      #pragma unroll
      for (int r = 0; r < 4; ++r) {
        // C/D layout (m89/m91): row = 4*(lane>>4)+reg, col = lane&15
        int li = wy * 64 + fi * 16 + l4 * 4 + r;
        int lj = wx * 64 + fj * 16 + l16;
        if (diag && li >= lj) continue;
        float s  = acc[fi][fj][r];
        float jf = floorf(s * STEPINV);
        int   jb = (int)jf + HALF_T;
        float f  = jf * STEPF;
        float wa = (s - f) * STEPINV;
        float wb = (f + STEPF - s) * STEPINV;
        bool  pos = (clsA[li] == clsB[lj]);
        *myPos += pos ? 1u : 0u;
        int off = pos ? 0 : TSIZE;
        if (jb >= 0 && jb < TSIZE)         unsafeAtomicAdd(h + off + jb, wa);
        if (jb + 1 >= 0 && jb + 1 < TSIZE) unsafeAtomicAdd(h + off + jb + 1, wb);
      }
    }
  }
}

__device__ __forceinline__ void tile_decode(int orig, int* bi_, int* bj_) {
  int sbid = (orig & 7) * 66 + (orig >> 3);      // XCD-bijective (528 = 8*66)
  int rem = sbid, cnt = NTILES, bi = 0;
  while (rem >= cnt) { rem -= cnt; --cnt; ++bi; }
  *bi_ = bi; *bj_ = bi + rem;
}

// ---- pass 1: split F -> fragment-major bf16 hi/lo [k/8][row][8] ----
// coalesced reads (consecutive threads -> consecutive 8-float chunks);
// 16B scattered writes are fire-and-forget. Also zeroes g_hist/g_pos.
__global__ __launch_bounds__(256) void presplit(
    const float* __restrict__ F, u16* __restrict__ FhiP, u16* __restrict__ FloP,
    float* __restrict__ g_hist, u32* __restrict__ g_pos)
{
  int u = blockIdx.x * 256 + threadIdx.x;   // u = row*64 + kb
  int row = u >> 6, kb = u & 63;
  const float* src = F + (size_t)row * DIM + kb * 8;
  float4 v0 = *(const float4*)(src);
  float4 v1 = *(const float4*)(src + 4);
  uint2 h0, l0, h1, l1;
  split4(v0, &h0, &l0);
  split4(v1, &h1, &l1);
  uint4 hv; hv.x = h0.x; hv.y = h0.y; hv.z = h1.x; hv.w = h1.y;
  uint4 lv; lv.x = l0.x; lv.y = l0.y; lv.z = l1.x; lv.w = l1.y;
  size_t dst = ((size_t)kb * N_PTS + row) * 8;
  *(uint4*)(FhiP + dst) = hv;
  *(uint4*)(FloP + dst) = lv;
  if (blockIdx.x == 0) {
    for (int i = threadIdx.x; i < 2 * TSIZE; i += 256) g_hist[i] = 0.0f;
    if (threadIdx.x == 0) *g_pos = 0u;
  }
}

// ---- pass 2: MFMA GEMM, register double-buffered K-pipeline ----
__global__ __launch_bounds__(256, 2) void hist_mfma(
    const u16* __restrict__ FhiP, const u16* __restrict__ FloP,
    const int* __restrict__ cls,
    float* __restrict__ g_hist, u32* __restrict__ g_pos)
{
  __shared__ float hist[NCOPY * HSTRIDE];
  __shared__ int clsA[BM], clsB[BM];
  __shared__ u32 posCount;

  const int t = threadIdx.x;
  int bi, bj;
  tile_decode((int)blockIdx.x, &bi, &bj);
  const int rowA = bi * BM, rowB = bj * BM;

  for (int i = t; i < NCOPY * HSTRIDE; i += 256) hist[i] = 0.0f;
  if (t < BM) clsA[t] = cls[rowA + t];
  else        clsB[t - BM] = cls[rowB + (t - BM)];
  if (t == 0) posCount = 0u;

  const int lane = t & 63, w = t >> 6;
  const int wy = w >> 1, wx = w & 1;          // wave -> 64x64 quadrant
  const int l4 = lane >> 4, l16 = lane & 15;

  ffrag acc[4][4] = {};

  const size_t SSTR = (size_t)4 * N_PTS * 8;  // elems per K-step plane
  const size_t lb   = (size_t)l4 * N_PTS * 8;
  const size_t ao   = lb + (size_t)(rowA + wy * 64 + l16) * 8;
  const size_t bo   = lb + (size_t)(rowB + wx * 64 + l16) * 8;
  const u16* pAh = FhiP + ao;
  const u16* pAl = FloP + ao;
  const u16* pBh = FhiP + bo;
  const u16* pBl = FloP + bo;

#define LOADF(ah, al, bh, bl, P)                                   \
  do {                                                             \
    _Pragma("unroll") for (int f = 0; f < 4; ++f) {                \
      ah[f] = *(const bfrag*)(pAh + (P) * SSTR + f * 128);         \
      al[f] = *(const bfrag*)(pAl + (P) * SSTR + f * 128);         \
      bh[f] = *(const bfrag*)(pBh + (P) * SSTR + f * 128);         \
      bl[f] = *(const bfrag*)(pBl + (P) * SSTR + f * 128);         \
    }                                                              \
  } while (0)

#define COMPUTE(ah, al, bh, bl)                                    \
  do {                                                             \
    _Pragma("unroll") for (int fj = 0; fj < 4; ++fj)               \
      _Pragma("unroll") for (int fi = 0; fi < 4; ++fi) {           \
        acc[fi][fj] = mfma16(ah[fi], bh[fj], acc[fi][fj]);         \
        acc[fi][fj] = mfma16(al[fi], bh[fj], acc[fi][fj]);         \
        acc[fi][fj] = mfma16(ah[fi], bl[fj], acc[fi][fj]);         \
      }                                                            \
  } while (0)

  bfrag a0h[4], a0l[4], b0h[4], b0l[4];
  bfrag a1h[4], a1l[4], b1h[4], b1l[4];

  LOADF(a0h, a0l, b0h, b0l, 0);
  #pragma unroll 1
  for (int s = 0; s < 7; ++s) {
    LOADF(a1h, a1l, b1h, b1l, 1);     // prefetch odd step
    COMPUTE(a0h, a0l, b0h, b0l);      // compute even step
    LOADF(a0h, a0l, b0h, b0l, 2);     // prefetch next even step
    COMPUTE(a1h, a1l, b1h, b1l);      // compute odd step
    pAh += 2 * SSTR; pAl += 2 * SSTR; pBh += 2 * SSTR; pBl += 2 * SSTR;
  }
  LOADF(a1h, a1l, b1h, b1l, 1);       // step 15
  COMPUTE(a0h, a0l, b0h, b0l);        // step 14
  COMPUTE(a1h, a1l, b1h, b1l);        // step 15

#undef LOADF
#undef COMPUTE

  __syncthreads();                    // hist/cls init visible
  u32 myPos = 0;
  float* h = hist + l16 * HSTRIDE;    // adjacent lanes -> distinct copies
  bin_epilogue(acc, h, clsA, clsB, wy, wx, l4, l16, bi == bj, &myPos);
  atomicAdd(&posCount, myPos);
  __syncthreads();

  for (int i = t; i < 2 * TSIZE; i += 256) {
    float v = 0.0f;
    #pragma unroll
    for (int c = 0; c < NCOPY; ++c) v += hist[c * HSTRIDE + i];
    unsafeAtomicAdd(g_hist + i, v);
  }
  if (t == 0) atomicAdd(g_pos, posCount);
}

__global__ __launch_bounds__(256) void finalize(
    const float* __restrict__ g_hist,
    const u32* __restrict__ g_pos,
    float* __restrict__ out)
{
  __shared__ float hp[TSIZE];
  __shared__ float hn[TSIZE];
  __shared__ float red[4];
  const int t = threadIdx.x;
  const float Np = (float)(*g_pos);
  const float Nn = (float)(P_TOTAL - *g_pos);
  if (t < TSIZE) {
    hp[t] = g_hist[t] / Np;
    hn[t] = g_hist[TSIZE + t] / Nn;
  }
  __syncthreads();
  for (int off = 1; off < TSIZE; off <<= 1) {
    float v = 0.0f;
    if (t < TSIZE && t >= off) v = hp[t - off];
    __syncthreads();
    if (t < TSIZE) hp[t] += v;
    __syncthreads();
  }
  float term = (t < TSIZE) ? hn[t] * hp[t] : 0.0f;
  #pragma unroll
  for (int o = 32; o > 0; o >>= 1) term += __shfl_down(term, o);
  if ((t & 63) == 0) red[t >> 6] = term;
  __syncthreads();
  if (t == 0) *out = red[0] + red[1] + red[2] + red[3];
}

extern "C" void kernel_launch(void* const* d_in, const int* in_sizes, int n_in,
                              void* d_out, int out_size, void* d_ws, size_t ws_size,
                              hipStream_t stream) {
  const float* F   = (const float*)d_in[0];
  const int*   cls = (const int*)d_in[1];
  float* g_hist = (float*)d_ws;
  u32*   g_pos  = (u32*)((char*)d_ws + 2 * TSIZE * sizeof(float));
  float* out = (float*)d_out;

  const size_t offH   = 65536;
  u16* FhiP = (u16*)((char*)d_ws + offH);
  u16* FloP = (u16*)((char*)d_ws + offH + (size_t)N_PTS * DIM * sizeof(u16));

  presplit<<<(N_PTS * 64) / 256, 256, 0, stream>>>(F, FhiP, FloP, g_hist, g_pos);
  hist_mfma<<<NBLOCKS, 256, 0, stream>>>(FhiP, FloP, cls, g_hist, g_pos);
  finalize<<<1, 256, 0, stream>>>(g_hist, g_pos, out);
}